// Round 2
// baseline (1972.318 us; speedup 1.0000x reference)
//
#include <hip/hip_runtime.h>
#include <math.h>

// RecurrentUnitAtt on MI355X — round 2 (resubmission; rounds 0-1 never ran:
// GPU acquisition timeout). All-f32, no MFMA.
// Pipeline: prep_weights (transpose 9 weight mats into ws) ->
//           transpose_p2 (points2 [B,64,N] -> row-major [B,N,64]) ->
//           knn_k (top-16 neighbor indices) ->
//           fused_main_k (gather + all convs/gates/pool/GRU update).

#define NPTS 4096
#define CF   64

// ---- ws float offsets for transposed weights ----
#define OFF_R0 0
#define OFF_Z0 4288
#define OFF_H0 8576
#define OFF_R1 12864
#define OFF_RO 16960
#define OFF_Z1 21056
#define OFF_H1 25152
#define OFF_FR 29248
#define OFF_FZ 33344

__global__ __launch_bounds__(256) void prep_weights_k(
    const float* __restrict__ w_r0, const float* __restrict__ w_z0,
    const float* __restrict__ w_h0, const float* __restrict__ w_r1,
    const float* __restrict__ w_ro, const float* __restrict__ w_z1,
    const float* __restrict__ w_h1, const float* __restrict__ w_fr,
    const float* __restrict__ w_fz, float* __restrict__ wT)
{
  const float* src; float* dst; int C;
  switch (blockIdx.x) {
    case 0: src = w_r0; dst = wT + OFF_R0; C = 67; break;
    case 1: src = w_z0; dst = wT + OFF_Z0; C = 67; break;
    case 2: src = w_h0; dst = wT + OFF_H0; C = 67; break;
    case 3: src = w_r1; dst = wT + OFF_R1; C = 64; break;
    case 4: src = w_ro; dst = wT + OFF_RO; C = 64; break;
    case 5: src = w_z1; dst = wT + OFF_Z1; C = 64; break;
    case 6: src = w_h1; dst = wT + OFF_H1; C = 64; break;
    case 7: src = w_fr; dst = wT + OFF_FR; C = 64; break;
    default: src = w_fz; dst = wT + OFF_FZ; C = 64; break;
  }
  const int total = C * 64;
  for (int e = threadIdx.x; e < total; e += 256) {
    int c = e >> 6, o = e & 63;
    dst[c * 64 + o] = src[o * C + c];   // wT[c][o] = w[o][c]
  }
}

__global__ __launch_bounds__(256) void transpose_p2_k(const float* __restrict__ p2,
                                                      float* __restrict__ p2T)
{
  __shared__ float tile[64][65];
  const int b  = blockIdx.x >> 6;
  const int n0 = (blockIdx.x & 63) * 64;
  const float* src = p2 + (size_t)b * CF * NPTS;
  for (int e = threadIdx.x; e < 4096; e += 256) {
    int c = e >> 6, nn = e & 63;
    tile[c][nn] = src[(size_t)c * NPTS + n0 + nn];
  }
  __syncthreads();
  float* dst = p2T + ((size_t)b * NPTS + n0) * CF;
  for (int e = threadIdx.x; e < 4096; e += 256) {
    int nn = e >> 6, c = e & 63;
    dst[(size_t)nn * CF + c] = tile[c][nn];
  }
}

// ---------------- kNN ----------------

__device__ __forceinline__ float max16_(const float (&ld)[16]) {
  float a0 = fmaxf(ld[0], ld[1]);
  float a1 = fmaxf(ld[2], ld[3]);
  float a2 = fmaxf(ld[4], ld[5]);
  float a3 = fmaxf(ld[6], ld[7]);
  float a4 = fmaxf(ld[8], ld[9]);
  float a5 = fmaxf(ld[10], ld[11]);
  float a6 = fmaxf(ld[12], ld[13]);
  float a7 = fmaxf(ld[14], ld[15]);
  a0 = fmaxf(a0, a1); a2 = fmaxf(a2, a3); a4 = fmaxf(a4, a5); a6 = fmaxf(a6, a7);
  return fmaxf(fmaxf(a0, a2), fmaxf(a4, a6));
}

// Replace the (unique, flagged) slot holding dmax, then rebuild dmax.
// Strict '<' guard outside keeps tie-breaking = lowest index (matches top_k).
__device__ __forceinline__ void insert16_(float (&ld)[16], int (&li)[16],
                                          float& dmax, float d, int m) {
  bool done = false;
  #pragma unroll
  for (int j = 0; j < 16; ++j) {
    bool hit = (!done) && (ld[j] == dmax);
    if (hit) { ld[j] = d; li[j] = m; }
    done = done || hit;
  }
  dmax = max16_(ld);
}

// block = 256 thr = 4 waves; 64 queries/block; wave w scans segment w.
// LDS stage of 2048 ref points per pass (float4 x,y,z,|x|^2), broadcast reads.
__global__ __launch_bounds__(256) void knn_k(const float* __restrict__ xyz1,
                                             const float* __restrict__ xyz2,
                                             int* __restrict__ idx_out)
{
  __shared__ float4 stage[2048];
  __shared__ float bd[4][64][17];           // +1 pad: conflict-free merge reads
  __shared__ unsigned short bix[4][64][17];
  const int t    = threadIdx.x;
  const int b    = blockIdx.x >> 6;
  const int q0   = (blockIdx.x & 63) * 64;
  const int lane = t & 63;
  const int seg  = t >> 6;
  const int q    = q0 + lane;
  const float* x1b = xyz1 + (size_t)b * 3 * NPTS;
  const float* x2b = xyz2 + (size_t)b * 3 * NPTS;
  const float qx = x1b[q], qy = x1b[NPTS + q], qz = x1b[2 * NPTS + q];
  const float qq = qx * qx + qy * qy + qz * qz;
  float ld[16]; int li[16];
  #pragma unroll
  for (int j = 0; j < 16; ++j) { ld[j] = 3.4e38f; li[j] = 0; }
  float dmax = 3.4e38f;
  for (int pass = 0; pass < 2; ++pass) {
    const int mbase = pass * 2048;
    for (int i = t; i < 2048; i += 256) {
      const int mm = mbase + i;
      float px = x2b[mm], py = x2b[NPTS + mm], pz = x2b[2 * NPTS + mm];
      stage[i] = make_float4(px, py, pz, px * px + py * py + pz * pz);
    }
    __syncthreads();
    const int s0 = seg * 512;
    #pragma unroll 4
    for (int i = 0; i < 512; ++i) {
      float4 P = stage[s0 + i];                       // wave-uniform -> broadcast
      float d = fmaf(-2.f, fmaf(qx, P.x, fmaf(qy, P.y, qz * P.z)), qq + P.w);
      if (d < dmax) insert16_(ld, li, dmax, d, mbase + s0 + i);
    }
    __syncthreads();
  }
  #pragma unroll
  for (int j = 0; j < 16; ++j) {
    bd[seg][lane][j]  = ld[j];
    bix[seg][lane][j] = (unsigned short)li[j];
  }
  __syncthreads();
  if (t < 64) {                                        // merge 4 lists -> final 16
    float md[16]; int mi[16];
    #pragma unroll
    for (int j = 0; j < 16; ++j) { md[j] = 3.4e38f; mi[j] = 0; }
    float mmax = 3.4e38f;
    for (int s = 0; s < 4; ++s) {
      #pragma unroll 4
      for (int j = 0; j < 16; ++j) {
        float d = bd[s][t][j];
        if (d < mmax) insert16_(md, mi, mmax, d, (int)bix[s][t][j]);
      }
    }
    int* op = idx_out + ((size_t)b * NPTS + q0 + t) * 16;
    #pragma unroll
    for (int j = 0; j < 16; ++j) op[j] = mi[j];
  }
}

// ---------------- fused gates ----------------

__device__ __forceinline__ float sigmoidf_(float x) { return 1.0f / (1.0f + __expf(-x)); }
__device__ __forceinline__ float leakyf_(float x)   { return x >= 0.0f ? x : 0.1f * x; }

__device__ __forceinline__ void fma16x4(const float* __restrict__ wr, float s, float (&acc)[64]) {
  #pragma unroll
  for (int o4 = 0; o4 < 16; ++o4) {
    float4 w = *(const float4*)(wr + o4 * 4);     // uniform addr -> s_load
    acc[o4 * 4 + 0] = fmaf(s, w.x, acc[o4 * 4 + 0]);
    acc[o4 * 4 + 1] = fmaf(s, w.y, acc[o4 * 4 + 1]);
    acc[o4 * 4 + 2] = fmaf(s, w.z, acc[o4 * 4 + 2]);
    acc[o4 * 4 + 3] = fmaf(s, w.w, acc[o4 * 4 + 3]);
  }
}

// acc[o] += sum_c np[c]*wT[c][o], np = p2T row (64) ++ direction (3)
__device__ __forceinline__ void conv0_acc(const float* __restrict__ nprow,
                                          float d0, float d1, float d2,
                                          const float* __restrict__ wT, float (&acc)[64])
{
  float4 v = *(const float4*)(nprow);
  #pragma unroll 1
  for (int c4 = 0; c4 < 16; ++c4) {
    float4 vn = *(const float4*)(nprow + ((c4 + 1) & 15) * 4);   // rotate prefetch
    const float* wb = wT + c4 * 256;
    fma16x4(wb,       v.x, acc);
    fma16x4(wb + 64,  v.y, acc);
    fma16x4(wb + 128, v.z, acc);
    fma16x4(wb + 192, v.w, acc);
    v = vn;
  }
  fma16x4(wT + 64 * 64, d0, acc);
  fma16x4(wT + 65 * 64, d1, acc);
  fma16x4(wT + 66 * 64, d2, acc);
}

__device__ __forceinline__ void init_bias_fuse(const float* __restrict__ bias,
                                               const float* fuse, float (&acc)[64]) {
  #pragma unroll
  for (int o4 = 0; o4 < 16; ++o4) {
    float4 bv = *(const float4*)(bias + o4 * 4);
    float4 fv = *(const float4*)(fuse + o4 * 4);
    acc[o4 * 4 + 0] = bv.x + fv.x;
    acc[o4 * 4 + 1] = bv.y + fv.y;
    acc[o4 * 4 + 2] = bv.z + fv.z;
    acc[o4 * 4 + 3] = bv.w + fv.w;
  }
}

__device__ __forceinline__ void init_bias(const float* __restrict__ bias, float (&acc)[64]) {
  #pragma unroll
  for (int o4 = 0; o4 < 16; ++o4) {
    float4 bv = *(const float4*)(bias + o4 * 4);
    acc[o4 * 4 + 0] = bv.x; acc[o4 * 4 + 1] = bv.y;
    acc[o4 * 4 + 2] = bv.z; acc[o4 * 4 + 3] = bv.w;
  }
}

// per-channel max over the 16 neighbor-lanes of each point (xor<16 stays in group)
__device__ __forceinline__ void kmax16(float (&a)[64]) {
  #pragma unroll
  for (int o = 0; o < 64; ++o) {
    float v = a[o];
    v = fmaxf(v, __shfl_xor(v, 1));
    v = fmaxf(v, __shfl_xor(v, 2));
    v = fmaxf(v, __shfl_xor(v, 4));
    v = fmaxf(v, __shfl_xor(v, 8));
    a[o] = v;
  }
}

// 4 outputs (o2 = k*4..k*4+3) of a pooled [64]->[64] layer; per-lane vector loads
__device__ __forceinline__ float4 gate1(const float (&pool)[64], const float* __restrict__ wT1,
                                        const float* __restrict__ b1, int k) {
  float4 bv = *(const float4*)(b1 + k * 4);
  float a0 = bv.x, a1 = bv.y, a2 = bv.z, a3 = bv.w;
  #pragma unroll
  for (int c = 0; c < 64; ++c) {
    float4 w = *(const float4*)(wT1 + c * 64 + k * 4);
    a0 = fmaf(pool[c], w.x, a0);
    a1 = fmaf(pool[c], w.y, a1);
    a2 = fmaf(pool[c], w.z, a2);
    a3 = fmaf(pool[c], w.w, a3);
  }
  return make_float4(a0, a1, a2, a3);
}

// block = 256 thr = 16 points; thread t -> (point q = t>>4, neighbor k = t&15)
__global__ __launch_bounds__(256) void fused_main_k(
    const float* __restrict__ xyz1, const float* __restrict__ xyz2,
    const float* __restrict__ p1,  const float* __restrict__ p2T,
    const int* __restrict__ knn_idx, const float* __restrict__ wT,
    const float* __restrict__ b_r0, const float* __restrict__ b_r1,
    const float* __restrict__ b_z0, const float* __restrict__ b_z1,
    const float* __restrict__ b_h0, const float* __restrict__ b_h1,
    float* __restrict__ out)
{
  __shared__ float p1s[16][68];   // 68-pad: 16B-aligned rows, no bank conflicts
  __shared__ float frs[16][68];
  __shared__ float fzs[16][68];
  const int blk = blockIdx.x;
  const int b   = blk >> 8;
  const int n0  = (blk & 255) * 16;
  const int t   = threadIdx.x;

  const float* p1b = p1 + (size_t)b * CF * NPTS;
  #pragma unroll
  for (int e = t; e < 1024; e += 256) {
    int c = e >> 4, qq = e & 15;
    p1s[qq][c] = p1b[(size_t)c * NPTS + n0 + qq];
  }
  __syncthreads();

  { // fuse_r / fuse_z (per point, no bias): thread -> (point, 4 out-channels)
    const int qq = t >> 4, o4 = (t & 15) * 4;
    const float* wfr = wT + OFF_FR;
    const float* wfz = wT + OFF_FZ;
    float fr0 = 0.f, fr1 = 0.f, fr2 = 0.f, fr3 = 0.f;
    float fz0 = 0.f, fz1 = 0.f, fz2 = 0.f, fz3 = 0.f;
    #pragma unroll 4
    for (int c = 0; c < 64; ++c) {
      float pv = p1s[qq][c];
      float4 wr = *(const float4*)(wfr + c * 64 + o4);
      float4 wz = *(const float4*)(wfz + c * 64 + o4);
      fr0 = fmaf(pv, wr.x, fr0); fr1 = fmaf(pv, wr.y, fr1);
      fr2 = fmaf(pv, wr.z, fr2); fr3 = fmaf(pv, wr.w, fr3);
      fz0 = fmaf(pv, wz.x, fz0); fz1 = fmaf(pv, wz.y, fz1);
      fz2 = fmaf(pv, wz.z, fz2); fz3 = fmaf(pv, wz.w, fz3);
    }
    *(float4*)(&frs[qq][o4]) = make_float4(fr0, fr1, fr2, fr3);
    *(float4*)(&fzs[qq][o4]) = make_float4(fz0, fz1, fz2, fz3);
  }
  __syncthreads();

  const int q = t >> 4;
  const int k = t & 15;
  const int n = n0 + q;
  const int m = knn_idx[((size_t)b * NPTS + n) * 16 + k];
  const float* x1b = xyz1 + (size_t)b * 3 * NPTS;
  const float* x2b = xyz2 + (size_t)b * 3 * NPTS;
  const float d0 = x2b[m]            - x1b[n];
  const float d1 = x2b[NPTS + m]     - x1b[NPTS + n];
  const float d2 = x2b[2 * NPTS + m] - x1b[2 * NPTS + n];
  const float* nprow = p2T + ((size_t)b * NPTS + m) * CF;

  // ---- z gate first (minimizes live registers) ----
  float z4x, z4y, z4z, z4w;
  {
    float zacc[64];
    init_bias_fuse(b_z0, &fzs[q][0], zacc);
    conv0_acc(nprow, d0, d1, d2, wT + OFF_Z0, zacc);
    #pragma unroll
    for (int o = 0; o < 64; ++o) zacc[o] = leakyf_(zacc[o]);
    kmax16(zacc);
    float4 a4 = gate1(zacc, wT + OFF_Z1, b_z1, k);
    z4x = sigmoidf_(a4.x); z4y = sigmoidf_(a4.y);
    z4z = sigmoidf_(a4.z); z4w = sigmoidf_(a4.w);
  }

  // ---- r gate ----
  float racc[64];
  init_bias_fuse(b_r0, &frs[q][0], racc);
  conv0_acc(nprow, d0, d1, d2, wT + OFF_R0, racc);
  #pragma unroll
  for (int o = 0; o < 64; ++o) racc[o] = leakyf_(racc[o]);

  // ---- fused r1 -> sigmoid -> (r*p1) -> pe, accumulated onto b_h0 ----
  float acch[64];
  init_bias(b_h0, acch);
  {
    const float* wr1 = wT + OFF_R1;
    const float* wro = wT + OFF_RO;
    #pragma unroll 1
    for (int c4 = 0; c4 < 16; ++c4) {
      float4 bv = *(const float4*)(b_r1 + c4 * 4);
      float a0 = bv.x, a1 = bv.y, a2 = bv.z, a3 = bv.w;
      #pragma unroll
      for (int ci = 0; ci < 64; ++ci) {
        float4 w = *(const float4*)(wr1 + ci * 64 + c4 * 4);
        a0 = fmaf(racc[ci], w.x, a0);
        a1 = fmaf(racc[ci], w.y, a1);
        a2 = fmaf(racc[ci], w.z, a2);
        a3 = fmaf(racc[ci], w.w, a3);
      }
      float4 p1v = *(const float4*)(&p1s[q][c4 * 4]);
      float rp0 = sigmoidf_(a0) * p1v.x;
      float rp1 = sigmoidf_(a1) * p1v.y;
      float rp2 = sigmoidf_(a2) * p1v.z;
      float rp3 = sigmoidf_(a3) * p1v.w;
      const float* wr = wro + c4 * 256;
      fma16x4(wr,       rp0, acch);
      fma16x4(wr + 64,  rp1, acch);
      fma16x4(wr + 128, rp2, acch);
      fma16x4(wr + 192, rp3, acch);
    }
  }

  // ---- h candidate: conv0_h + pe, leaky, pool, h1, tanh ----
  conv0_acc(nprow, d0, d1, d2, wT + OFF_H0, acch);
  #pragma unroll
  for (int o = 0; o < 64; ++o) acch[o] = leakyf_(acch[o]);
  kmax16(acch);
  float4 h4 = gate1(acch, wT + OFF_H1, b_h1, k);
  const float hx = tanhf(h4.x), hy = tanhf(h4.y), hz = tanhf(h4.z), hw = tanhf(h4.w);

  // ---- GRU update, store out[b][o][n] ----
  float4 p1v = *(const float4*)(&p1s[q][k * 4]);
  float* ob = out + (size_t)b * CF * NPTS + n;
  ob[(size_t)(k * 4 + 0) * NPTS] = (1.f - z4x) * p1v.x + z4x * hx;
  ob[(size_t)(k * 4 + 1) * NPTS] = (1.f - z4y) * p1v.y + z4y * hy;
  ob[(size_t)(k * 4 + 2) * NPTS] = (1.f - z4z) * p1v.z + z4z * hz;
  ob[(size_t)(k * 4 + 3) * NPTS] = (1.f - z4w) * p1v.w + z4w * hw;
}

extern "C" void kernel_launch(void* const* d_in, const int* in_sizes, int n_in,
                              void* d_out, int out_size, void* d_ws, size_t ws_size,
                              hipStream_t stream)
{
  (void)in_sizes; (void)n_in; (void)out_size; (void)ws_size;
  const float* xyz1 = (const float*)d_in[0];
  const float* xyz2 = (const float*)d_in[1];
  const float* p1   = (const float*)d_in[2];
  const float* p2   = (const float*)d_in[3];
  const float* w_fr = (const float*)d_in[4];
  const float* w_fz = (const float*)d_in[5];
  const float* w_ro = (const float*)d_in[6];
  const float* w_r0 = (const float*)d_in[7];
  const float* b_r0 = (const float*)d_in[8];
  const float* w_r1 = (const float*)d_in[9];
  const float* b_r1 = (const float*)d_in[10];
  const float* w_z0 = (const float*)d_in[11];
  const float* b_z0 = (const float*)d_in[12];
  const float* w_z1 = (const float*)d_in[13];
  const float* b_z1 = (const float*)d_in[14];
  const float* w_h0 = (const float*)d_in[15];
  const float* b_h0 = (const float*)d_in[16];
  const float* w_h1 = (const float*)d_in[17];
  const float* b_h1 = (const float*)d_in[18];

  char* ws = (char*)d_ws;
  int*   idx_ws = (int*)ws;                        // 8*4096*16*4   = 2 MiB
  float* p2T    = (float*)(ws + 2097152);          // 8*4096*64*4   = 8 MiB
  float* wT     = (float*)(ws + 10485760);         // 37440 floats  ~ 146 KiB
  float* out    = (float*)d_out;

  prep_weights_k<<<9, 256, 0, stream>>>(w_r0, w_z0, w_h0, w_r1, w_ro,
                                        w_z1, w_h1, w_fr, w_fz, wT);
  transpose_p2_k<<<512, 256, 0, stream>>>(p2, p2T);
  knn_k<<<512, 256, 0, stream>>>(xyz1, xyz2, idx_ws);
  fused_main_k<<<2048, 256, 0, stream>>>(xyz1, xyz2, p1, p2T, idx_ws, wT,
                                         b_r0, b_r1, b_z0, b_z1, b_h0, b_h1, out);
}